// Round 14
// baseline (14142.686 us; speedup 1.0000x reference)
//
#include <hip/hip_runtime.h>

#define B_ 16
#define S_ 1024
#define H_ 512
#define E_ 512
#define L_ 10

typedef float f4_t __attribute__((ext_vector_type(4)));
typedef __attribute__((address_space(1))) void gas_void;
typedef __attribute__((address_space(3))) void las_void;

__device__ __forceinline__ float frcp_(float x)
{
    float r;
    asm("v_rcp_f32 %0, %1" : "=v"(r) : "v"(x));
    return r;
}
__device__ __forceinline__ float fsig_(float x) { return frcp_(1.0f + __expf(-x)); }
__device__ __forceinline__ float ftanh_(float x)
{
    const float e = __expf(-2.0f * fabsf(x));
    const float r = (1.0f - e) * frcp_(1.0f + e);
    return copysignf(r, x);
}

// Write-through store: bypasses L1/L2 (sc0 sc1), lands at LLC once acked.
__device__ __forceinline__ void store_wt4(float* p, f4_t v)
{
    asm volatile("global_store_dwordx4 %0, %1, off sc0 sc1" :: "v"(p), "v"(v) : "memory");
}

// Async global->LDS DMA: per-lane global src, wave-uniform LDS base + lane*16.
__device__ __forceinline__ void gll16(const float* g, float* l)
{
    __builtin_amdgcn_global_load_lds((const gas_void*)g, (las_void*)l, 16, 0, 0);
}

#define WAITV0() asm volatile("s_waitcnt vmcnt(0)" ::: "memory")
#define WAITV2() asm volatile("s_waitcnt vmcnt(2)" ::: "memory")
// raw barrier: drains LDS ops only, keeps GLL/global prefetches in flight
#define BAR() do { asm volatile("s_waitcnt lgkmcnt(0)" ::: "memory"); \
                   __builtin_amdgcn_s_barrier(); } while (0)

// ---------------------------------------------------------------- embedding
__global__ __launch_bounds__(128) void embed_kernel(const int* __restrict__ tokens,
                                                    const float* __restrict__ emb,
                                                    float* __restrict__ x0)
{
    const int row = blockIdx.x;              // b*S + s
    const int tok = tokens[row];
    const float4* src = (const float4*)(emb + (size_t)tok * E_);
    float4* dst = (float4*)(x0 + (size_t)row * E_);
    dst[threadIdx.x] = src[threadIdx.x];
}

// ---------------------------------------------------------------- bidirectional LSTM layer
// Persistent, 256 blocks (1/CU), 1024 THREADS (16 waves, 4/SIMD, occ 50%).
// r11 (2 waves/SIMD) gave +10% over 1 wave/SIMD; latency-bound regime
// (VALU 25%, HBM 1.4%) -> more TLP compresses J/K/M and hides the h-load
// + L2 weight stream. Protocol/structure = r13 (publish at M-end with
// ack covered by GLL issue; poll after first E phase; column-half h
// staging, 1 flag/thread). K split 64 ways (8 cols/slice); s_red 16
// partials; LDS 153KB (still 1 block/CU). All staging via
// global_load_lds; NO cross-phase register arrays (r4-r6/r9 lesson).
#define GLL_TILE(DST, SRC, RS)                                      \
    _Pragma("unroll")                                               \
    for (int k = 0; k < 2; ++k) {                                   \
        const int m_  = (wvi << 1) | k;                             \
        const int rr_ = m_ >> 1;                                    \
        const int ch_ = (m_ & 1) << 8;                              \
        gll16((SRC) + (size_t)rr_ * (RS) + ch_ + lane * 4,          \
              (DST) + rr_ * 516 + ch_);                             \
    }

// h tile: waves 0-7 cols 0-255 (rows 2(w&7),+1), waves 8-15 cols 256-511
#define GLL_TILE_H(DST, SRC, RS)                                    \
    _Pragma("unroll")                                               \
    for (int k = 0; k < 2; ++k) {                                   \
        const int rr_ = ((wvi & 7) << 1) | k;                       \
        const int ch_ = (wvi >> 3) << 8;                            \
        gll16((SRC) + (size_t)rr_ * (RS) + ch_ + lane * 4,          \
              (DST) + rr_ * 516 + ch_);                             \
    }

// CN-chunk slice of the 4x4-microtile GEMM; 64 k-slices of 8 cols each
#define EG(PP, WEXPR, CB, CN)                                                 \
    _Pragma("unroll")                                                         \
    for (int cc = (CB); cc < (CB) + (CN); ++cc) {                             \
        const int scol = kb + (((cc + ks) & 1) << 2);                         \
        const float4 hv0 = *(const float4*)&(PP)[(b40 + 0) * 516 + scol];     \
        const float4 hv1 = *(const float4*)&(PP)[(b40 + 1) * 516 + scol];     \
        const float4 hv2 = *(const float4*)&(PP)[(b40 + 2) * 516 + scol];     \
        const float4 hv3 = *(const float4*)&(PP)[(b40 + 3) * 516 + scol];     \
        _Pragma("unroll")                                                     \
        for (int j = 0; j < 4; ++j) {                                         \
            const float4 wv = (WEXPR);                                        \
            acc[j*4+0] = fmaf(wv.x, hv0.x, acc[j*4+0]);                       \
            acc[j*4+0] = fmaf(wv.y, hv0.y, acc[j*4+0]);                       \
            acc[j*4+0] = fmaf(wv.z, hv0.z, acc[j*4+0]);                       \
            acc[j*4+0] = fmaf(wv.w, hv0.w, acc[j*4+0]);                       \
            acc[j*4+1] = fmaf(wv.x, hv1.x, acc[j*4+1]);                       \
            acc[j*4+1] = fmaf(wv.y, hv1.y, acc[j*4+1]);                       \
            acc[j*4+1] = fmaf(wv.z, hv1.z, acc[j*4+1]);                       \
            acc[j*4+1] = fmaf(wv.w, hv1.w, acc[j*4+1]);                       \
            acc[j*4+2] = fmaf(wv.x, hv2.x, acc[j*4+2]);                       \
            acc[j*4+2] = fmaf(wv.y, hv2.y, acc[j*4+2]);                       \
            acc[j*4+2] = fmaf(wv.z, hv2.z, acc[j*4+2]);                       \
            acc[j*4+2] = fmaf(wv.w, hv2.w, acc[j*4+2]);                       \
            acc[j*4+3] = fmaf(wv.x, hv3.x, acc[j*4+3]);                       \
            acc[j*4+3] = fmaf(wv.y, hv3.y, acc[j*4+3]);                       \
            acc[j*4+3] = fmaf(wv.z, hv3.z, acc[j*4+3]);                       \
            acc[j*4+3] = fmaf(wv.w, hv3.w, acc[j*4+3]);                       \
        }                                                                     \
    }

// poll: 1 flag/thread; wave covers the 64 producers of its column half
#define POLL1()                                                               \
    do {                                                                      \
        int* fp_ = &flags[(dir << 7) + ((wvi >> 3) << 6) + (tid & 63)];       \
        while (__hip_atomic_load(fp_, __ATOMIC_RELAXED,                       \
                                 __HIP_MEMORY_SCOPE_AGENT) < step) { }        \
        asm volatile("" ::: "memory");                                        \
    } while (0)

template<int DIN>
__global__ __launch_bounds__(1024, 4) void lstm_bidir(
    const float* __restrict__ x,
    const float* __restrict__ wihF, const float* __restrict__ whhF,
    const float* __restrict__ bihF, const float* __restrict__ bhhF,
    const float* __restrict__ wihR, const float* __restrict__ whhR,
    const float* __restrict__ bihR, const float* __restrict__ bhhR,
    float* __restrict__ hs,          // (B, S, 1024): [0:512]=fwd, [512:1024]=rev
    int* __restrict__ flags)         // 256 ints, flags[bid]
{
    constexpr int NH = DIN / 512;    // 1 (l0) or 2 (l1)

    const int tid = threadIdx.x;
    const int bid = blockIdx.x;
    const int dir = bid >> 7;
    const int c0  = (bid & 127) << 2;

    const float* wih = dir ? wihR : wihF;
    const float* whh = dir ? whhR : whhF;
    const float* bih = dir ? bihR : bihF;
    const float* bhh = dir ? bhhR : bhhF;

    __shared__ __align__(16) float s_wih[16 * 516];   // W_ih cols 0..511
    __shared__ __align__(16) float s_whh[16 * 516];
    __shared__ __align__(16) float s_P[16 * 516];
    __shared__ __align__(16) float s_Q[16 * 516];
    __shared__ __align__(16) float s_red[16][16][20];
    __shared__ float s_bias[16];

    for (int r = 0; r < 16; ++r) {
        const int grow = ((r >> 2) * H_) + c0 + (r & 3);
        const float* srcI = wih + (size_t)grow * DIN;
        for (int i = tid; i < 128; i += 1024)
            *(float4*)&s_wih[r * 516 + i * 4] = *(const float4*)&srcI[i * 4];
        const float* srcH = whh + (size_t)grow * H_;
        for (int i = tid; i < 128; i += 1024)
            *(float4*)&s_whh[r * 516 + i * 4] = *(const float4*)&srcH[i * 4];
    }
    if (tid < 16) {
        const int grow = ((tid >> 2) * H_) + c0 + (tid & 3);
        s_bias[tid] = bih[grow] + bhh[grow];
    }

    const int rb   = tid & 15;
    const int ks   = tid >> 4;        // k-slice 0..63 (8 cols each)
    const int r40  = (rb >> 2) << 2;
    const int b40  = (rb & 3) << 2;
    const int kb   = ks << 3;
    const int lane = tid & 63;
    const int wvi  = tid >> 6;        // wave 0..15

    float cstate = 0.0f;              // meaningful for tid<64
    float acc[16];

    {   // prologue: stage x(t0)
        const int t0 = dir ? (S_ - 1) : 0;
        GLL_TILE(s_P, x + (size_t)t0 * DIN, (size_t)S_ * DIN);
        if (NH == 2) GLL_TILE(s_Q, x + (size_t)t0 * DIN + 512, (size_t)S_ * DIN);
    }

    for (int step = 0; step < S_; ++step) {
        const int t  = dir ? (S_ - 1 - step) : step;
        const int sn = (step + 1 < S_) ? (step + 1) : (S_ - 1);
        const int tn = dir ? (S_ - 1 - sn) : sn;
        const int tp = dir ? (t + 1) : (t - 1);

        // ---- top: drain own GLL x prefetch
        WAITV0();
        BAR();

        #pragma unroll
        for (int a = 0; a < 16; ++a) acc[a] = 0.0f;

        if constexpr (NH == 2) {
            // E1: x(t) half1 (Q) x W_ih[:,512:] streamed from L2/L1
            EG(s_Q, (*(const float4*)&wih[(size_t)((r40 >> 2) * H_ + c0 + j) * DIN + 512 + scol]), 0, 2);
            BAR();                        // Q consumed by all waves
            if (step > 0) {               // flag propagated during E1
                POLL1();
                GLL_TILE_H(s_Q, hs + (size_t)tp * 1024 + dir * 512, (size_t)S_ * 1024);
            }
            // E0: x(t) half0 (P) x LDS W_ih -- h DMA flies under it
            EG(s_P, (*(const float4*)&s_wih[(r40 + j) * 516 + scol]), 0, 2);
        } else {
            // E_a: first half of x-part (flag propagates during it)
            EG(s_P, (*(const float4*)&s_wih[(r40 + j) * 516 + scol]), 0, 1);
            if (step > 0) {
                POLL1();
                GLL_TILE_H(s_Q, hs + (size_t)tp * 1024 + dir * 512, (size_t)S_ * 1024);
            }
            // E_b: second half hides the h DMA
            EG(s_P, (*(const float4*)&s_wih[(r40 + j) * 516 + scol]), 1, 1);
        }

        WAITV0();                         // own h-GLL share landed
        BAR();                            // all waves' shares landed; P free

        GLL_TILE(s_P, x + (size_t)tn * DIN, (size_t)S_ * DIN);   // x(t+1) h0

        if (step > 0) {                   // J: gates += h @ W_hh^T
            EG(s_Q, (*(const float4*)&s_whh[(r40 + j) * 516 + scol]), 0, 2);
        }

        // K: reduce 4 in-wave k-slices, then 16 wave partials via s_red
        #pragma unroll
        for (int a = 0; a < 16; ++a) {
            float v = acc[a];
            v += __shfl_xor(v, 16);
            v += __shfl_xor(v, 32);
            acc[a] = v;
        }
        if ((tid & 63) < 16) {
            float* base = &s_red[wvi][tid & 15][0];
            #pragma unroll
            for (int q = 0; q < 4; ++q)
                *(float4*)&base[q * 4] =
                    make_float4(acc[q * 4 + 0], acc[q * 4 + 1], acc[q * 4 + 2], acc[q * 4 + 3]);
        }
        BAR();                            // s_red ready; Q free

        // M: cell update + WT store (wave 0; ack covered by GLL_Q issue)
        if (tid < 64) {
            const int c = tid >> 4, b = tid & 15;
            float g[4];
            #pragma unroll
            for (int gg = 0; gg < 4; ++gg) {
                const int rbv = (gg << 2) | (b >> 2);
                const int av  = (c << 2) | (b & 3);
                float s = s_bias[gg * 4 + c];
                #pragma unroll
                for (int w = 0; w < 16; ++w) s += s_red[w][rbv][av];
                g[gg] = s;
            }
            const float iv = fsig_(g[0]);
            const float fv = fsig_(g[1]);
            const float gv = ftanh_(g[2]);
            const float ov = fsig_(g[3]);
            cstate = fv * cstate + iv * gv;
            const float hval = ov * ftanh_(cstate);
            f4_t o;                          // gather 4 cells of one batch
            o.x = hval;
            o.y = __shfl(hval, tid + 16);
            o.z = __shfl(hval, tid + 32);
            o.w = __shfl(hval, tid + 48);
            if (tid < 16)
                store_wt4(&hs[(size_t)(b * S_ + t) * 1024 + dir * 512 + c0], o);
        }
        if constexpr (NH == 2)            // issue BEFORE the ack wait: covers it
            GLL_TILE(s_Q, x + (size_t)tn * DIN + 512, (size_t)S_ * DIN);
        if (tid < 64) {
            if (NH == 2) { WAITV2(); }    // drains only the older WT stores
            else         { WAITV0(); }
            if (tid == 0)                 // publish h(t): M-end, max slack
                __hip_atomic_store(&flags[bid], step + 1,
                                   __ATOMIC_RELAXED, __HIP_MEMORY_SCOPE_AGENT);
        }
    }
}

// ---------------------------------------------------------------- out proj + argmax -> mask
__global__ __launch_bounds__(256) void outproj_kernel(
    const float* __restrict__ x1, const float* __restrict__ out_w,
    const float* __restrict__ out_b, float* __restrict__ res,
    unsigned char* __restrict__ mask)
{
    const int tid  = threadIdx.x;
    const int lane = tid & 63;
    const int w    = tid >> 6;
    const int row  = blockIdx.x * 4 + w;     // b*S + s
    const float* xr = x1 + (size_t)row * 1024;
    float4 xv[4];
    #pragma unroll
    for (int i = 0; i < 4; ++i) xv[i] = *(const float4*)&xr[(i * 64 + lane) << 2];
    float best = -__builtin_inff();
    int bi = 0;
    #pragma unroll
    for (int l = 0; l < L_; ++l) {
        const float* wr = out_w + l * 1024;
        float s = 0.0f;
        #pragma unroll
        for (int i = 0; i < 4; ++i) {
            const float4 wv = *(const float4*)&wr[(i * 64 + lane) << 2];
            s = fmaf(xv[i].x, wv.x, s);
            s = fmaf(xv[i].y, wv.y, s);
            s = fmaf(xv[i].z, wv.z, s);
            s = fmaf(xv[i].w, wv.w, s);
        }
        #pragma unroll
        for (int d = 32; d >= 1; d >>= 1) s += __shfl_xor(s, d);
        s += out_b[l];
        if (lane == l) res[(size_t)row * L_ + l] = s;
        if (s > best) { best = s; bi = l; }     // strict > keeps first index (jnp.argmax)
    }
    if (lane == 0) mask[row] = (unsigned char)(bi != 0);
}

// ---------------------------------------------------------------- batched fp32 GEMM 64x64x16
// MODE 0: C = A @ B^T ; MODE 1: C = A @ B + D
template<int MODE>
__global__ __launch_bounds__(256) void gemm64(
    const float* __restrict__ A, const float* __restrict__ Bm,
    const float* __restrict__ D, float* __restrict__ C,
    const int M, const int N, const int K)
{
    const int bz = blockIdx.z;
    const float* Ab = A  + (size_t)bz * M * K;
    const float* Bb = Bm + (size_t)bz * N * K;
    const float* Db = (MODE == 1) ? (D + (size_t)bz * M * N) : (const float*)nullptr;
    float* Cb = C + (size_t)bz * M * N;
    const int m0 = blockIdx.y << 6;
    const int n0 = blockIdx.x << 6;
    const int tid = threadIdx.x;
    const int tm = tid >> 4, tn = tid & 15;
    const int am = tid >> 2, ak = (tid & 3) << 2;
    const int bk1 = tid >> 4, bn1 = (tid & 15) << 2;
    __shared__ float As[16][68];
    __shared__ float Bs[16][68];
    float acc[4][4] = {};
    for (int k0 = 0; k0 < K; k0 += 16) {
        const float4 av = *(const float4*)&Ab[(size_t)(m0 + am) * K + k0 + ak];
        float4 bv;
        if (MODE == 0) bv = *(const float4*)&Bb[(size_t)(n0 + am) * K + k0 + ak];
        else           bv = *(const float4*)&Bb[(size_t)(k0 + bk1) * N + n0 + bn1];
        __syncthreads();
        As[ak + 0][am] = av.x; As[ak + 1][am] = av.y;
        As[ak + 2][am] = av.z; As[ak + 3][am] = av.w;
        if (MODE == 0) {
            Bs[ak + 0][am] = bv.x; Bs[ak + 1][am] = bv.y;
            Bs[ak + 2][am] = bv.z; Bs[ak + 3][am] = bv.w;
        } else {
            *(float4*)&Bs[bk1][bn1] = bv;
        }
        __syncthreads();
        #pragma unroll
        for (int k = 0; k < 16; ++k) {
            const float4 a4 = *(const float4*)&As[k][tm << 2];
            const float4 b4 = *(const float4*)&Bs[k][tn << 2];
            acc[0][0] = fmaf(a4.x, b4.x, acc[0][0]); acc[0][1] = fmaf(a4.x, b4.y, acc[0][1]);
            acc[0][2] = fmaf(a4.x, b4.z, acc[0][2]); acc[0][3] = fmaf(a4.x, b4.w, acc[0][3]);
            acc[1][0] = fmaf(a4.y, b4.x, acc[1][0]); acc[1][1] = fmaf(a4.y, b4.y, acc[1][1]);
            acc[1][2] = fmaf(a4.y, b4.z, acc[1][2]); acc[1][3] = fmaf(a4.y, b4.w, acc[1][3]);
            acc[2][0] = fmaf(a4.z, b4.x, acc[2][0]); acc[2][1] = fmaf(a4.z, b4.y, acc[2][1]);
            acc[2][2] = fmaf(a4.z, b4.z, acc[2][2]); acc[2][3] = fmaf(a4.z, b4.w, acc[2][3]);
            acc[3][0] = fmaf(a4.w, b4.x, acc[3][0]); acc[3][1] = fmaf(a4.w, b4.y, acc[3][1]);
            acc[3][2] = fmaf(a4.w, b4.z, acc[3][2]); acc[3][3] = fmaf(a4.w, b4.w, acc[3][3]);
        }
    }
    #pragma unroll
    for (int j = 0; j < 4; ++j) {
        const size_t ci = (size_t)(m0 + (tm << 2) + j) * N + n0 + (tn << 2);
        float4 o = make_float4(acc[j][0], acc[j][1], acc[j][2], acc[j][3]);
        if (MODE == 1) {
            const float4 dv = *(const float4*)&Db[ci];
            o.x += dv.x; o.y += dv.y; o.z += dv.z; o.w += dv.w;
        }
        *(float4*)&Cb[ci] = o;
    }
}

// ---------------------------------------------------------------- dual masked softmax (in place)
__global__ __launch_bounds__(256) void softmax_kernel(float* __restrict__ sc,
                                                      const unsigned char* __restrict__ mask)
{
    const float INF = __builtin_inff();
    const int row = blockIdx.x;          // b*S + s
    const int b = row >> 10;
    float* pr = sc + (size_t)row * 1024;
    const unsigned char* mr = mask + b * 1024;
    const int tid = threadIdx.x;
    const int lane = tid & 63;
    const int w = tid >> 6;
    const int j0 = tid << 2;
    const float4 v = *(const float4*)&pr[j0];
    const unsigned mu = *(const unsigned*)&mr[j0];
    const bool m0 = (mu & 0xffu) != 0, m1 = ((mu >> 8) & 0xffu) != 0;
    const bool m2 = ((mu >> 16) & 0xffu) != 0, m3 = ((mu >> 24) & 0xffu) != 0;

    float mme = -INF, mot = -INF;
    if (m0) mme = fmaxf(mme, v.x); else mot = fmaxf(mot, v.x);
    if (m1) mme = fmaxf(mme, v.y); else mot = fmaxf(mot, v.y);
    if (m2) mme = fmaxf(mme, v.z); else mot = fmaxf(mot, v.z);
    if (m3) mme = fmaxf(mme, v.w); else mot = fmaxf(mot, v.w);
    #pragma unroll
    for (int d = 32; d >= 1; d >>= 1) {
        mme = fmaxf(mme, __shfl_xor(mme, d));
        mot = fmaxf(mot, __shfl_xor(mot, d));
    }
    __shared__ float sm[2][4];
    if (lane == 0) { sm[0][w] = mme; sm[1][w] = mot; }
    __syncthreads();
    float Mme = fmaxf(fmaxf(sm[0][0], sm[0][1]), fmaxf(sm[0][2], sm[0][3]));
    float Mot = fmaxf(fmaxf(sm[1][0], sm[1][1]), fmaxf(sm[1][2], sm[1][3]));
    const float MmeU = (Mme == -INF) ? 0.0f : Mme;
    const float MotU = (Mot == -INF) ? 0.0f : Mot;

    const float e0 = expf(v.x - (m0 ? MmeU : MotU));
    const float e1 = expf(v.y - (m1 ? MmeU : MotU));
    const float e2 = expf(v.z - (m2 ? MmeU : MotU));
    const float e3 = expf(v.w - (m3 ? MmeU : MotU));
    float sme = 0.0f, sot = 0.0f;
    if (m0) sme += e0; else sot += e0;
    if (m1) sme += e1; else sot += e1;
    if (m2) sme += e2; else sot += e2;
    if (m3) sme += e3; else sot += e3;
    #pragma unroll
    for (int d = 32; d >= 1; d >>= 1) {
        sme += __shfl_xor(sme, d);
        sot += __shfl_xor(sot, d);
    }
    __syncthreads();
    if (lane == 0) { sm[0][w] = sme; sm[1][w] = sot; }
    __syncthreads();
    const float Dme = sm[0][0] + sm[0][1] + sm[0][2] + sm[0][3];
    const float Dot = sm[1][0] + sm[1][1] + sm[1][2] + sm[1][3];

    float4 o;
    o.x = m0 ? (Dme > 0.0f ? e0 / Dme : 0.0f) : (Dot > 0.0f ? e0 / Dot : 0.0f);
    o.y = m1 ? (Dme > 0.0f ? e1 / Dme : 0.0f) : (Dot > 0.0f ? e1 / Dot : 0.0f);
    o.z = m2 ? (Dme > 0.0f ? e2 / Dme : 0.0f) : (Dot > 0.0f ? e2 / Dot : 0.0f);
    o.w = m3 ? (Dme > 0.0f ? e3 / Dme : 0.0f) : (Dot > 0.0f ? e3 / Dot : 0.0f);
    *(float4*)&pr[j0] = o;
}

// ---------------------------------------------------------------- launch
extern "C" void kernel_launch(void* const* d_in, const int* in_sizes, int n_in,
                              void* d_out, int out_size, void* d_ws, size_t ws_size,
                              hipStream_t stream)
{
    const float* emb     = (const float*)d_in[0];
    const float* wih_l0  = (const float*)d_in[1];
    const float* whh_l0  = (const float*)d_in[2];
    const float* bih_l0  = (const float*)d_in[3];
    const float* bhh_l0  = (const float*)d_in[4];
    const float* wih_l0r = (const float*)d_in[5];
    const float* whh_l0r = (const float*)d_in[6];
    const float* bih_l0r = (const float*)d_in[7];
    const float* bhh_l0r = (const float*)d_in[8];
    const float* wih_l1  = (const float*)d_in[9];
    const float* whh_l1  = (const float*)d_in[10];
    const float* bih_l1  = (const float*)d_in[11];
    const float* bhh_l1  = (const float*)d_in[12];
    const float* wih_l1r = (const float*)d_in[13];
    const float* whh_l1r = (const float*)d_in[14];
    const float* bih_l1r = (const float*)d_in[15];
    const float* bhh_l1r = (const float*)d_in[16];
    const float* out_w   = (const float*)d_in[17];
    const float* out_b   = (const float*)d_in[18];
    const int*   tokens  = (const int*)d_in[19];

    float* out     = (float*)d_out;
    float* A_out   = out;                          // (16,1024,1024)
    float* res_out = out + 16777216;               // (16,1024,10)

    float* ws = (float*)d_ws;
    float* x0 = ws;                                //  8,388,608 f
    float* h0 = ws + 8388608;                      // 16,777,216 f
    float* x1 = h0 + 16777216;                     // 16,777,216 f
    float* sc = x1 + 16777216;                     // 16,777,216 f (scores, then P in place)
    unsigned char* mask = (unsigned char*)(sc + 16777216);   // 16,384 B
    int* flags0 = (int*)(mask + 16384);            // 256 ints
    int* flags1 = flags0 + 256;

    (void)in_sizes; (void)n_in; (void)out_size; (void)ws_size;

    (void)hipMemsetAsync(flags0, 0, 512 * sizeof(int), stream);

    embed_kernel<<<B_ * S_, 128, 0, stream>>>(tokens, emb, x0);

    lstm_bidir<512><<<256, 1024, 0, stream>>>(
        x0, wih_l0, whh_l0, bih_l0, bhh_l0,
        wih_l0r, whh_l0r, bih_l0r, bhh_l0r, h0, flags0);

    lstm_bidir<1024><<<256, 1024, 0, stream>>>(
        h0, wih_l1, whh_l1, bih_l1, bhh_l1,
        wih_l1r, whh_l1r, bih_l1r, bhh_l1r, x1, flags1);

    outproj_kernel<<<(B_ * S_) / 4, 256, 0, stream>>>(x1, out_w, out_b, res_out, mask);

    dim3 gg(16, 16, 16);
    gemm64<0><<<gg, 256, 0, stream>>>(x1, x1, nullptr, sc, 1024, 1024, 1024);

    softmax_kernel<<<B_ * S_, 256, 0, stream>>>(sc, mask);

    gemm64<1><<<gg, 256, 0, stream>>>(sc, x1, x1, A_out, 1024, 1024, 1024);
}

// Round 15
// 12604.097 us; speedup vs baseline: 1.1221x; 1.1221x over previous
//
#include <hip/hip_runtime.h>

#define B_ 16
#define S_ 1024
#define H_ 512
#define E_ 512
#define L_ 10

typedef float f4_t __attribute__((ext_vector_type(4)));
typedef __attribute__((address_space(1))) void gas_void;
typedef __attribute__((address_space(3))) void las_void;

__device__ __forceinline__ float frcp_(float x)
{
    float r;
    asm("v_rcp_f32 %0, %1" : "=v"(r) : "v"(x));
    return r;
}
__device__ __forceinline__ float fsig_(float x) { return frcp_(1.0f + __expf(-x)); }
__device__ __forceinline__ float ftanh_(float x)
{
    const float e = __expf(-2.0f * fabsf(x));
    const float r = (1.0f - e) * frcp_(1.0f + e);
    return copysignf(r, x);
}

// Write-through store: bypasses L1/L2 (sc0 sc1), lands at LLC once acked.
__device__ __forceinline__ void store_wt4(float* p, f4_t v)
{
    asm volatile("global_store_dwordx4 %0, %1, off sc0 sc1" :: "v"(p), "v"(v) : "memory");
}

// Async global->LDS DMA: per-lane global src, wave-uniform LDS base + lane*16.
__device__ __forceinline__ void gll16(const float* g, float* l)
{
    __builtin_amdgcn_global_load_lds((const gas_void*)g, (las_void*)l, 16, 0, 0);
}

#define WAITV0() asm volatile("s_waitcnt vmcnt(0)" ::: "memory")
#define WAITV4() asm volatile("s_waitcnt vmcnt(4)" ::: "memory")
// raw barrier: drains LDS ops only, keeps GLL/global prefetches in flight
#define BAR() do { asm volatile("s_waitcnt lgkmcnt(0)" ::: "memory"); \
                   __builtin_amdgcn_s_barrier(); } while (0)

// ---------------------------------------------------------------- embedding
__global__ __launch_bounds__(128) void embed_kernel(const int* __restrict__ tokens,
                                                    const float* __restrict__ emb,
                                                    float* __restrict__ x0)
{
    const int row = blockIdx.x;              // b*S + s
    const int tok = tokens[row];
    const float4* src = (const float4*)(emb + (size_t)tok * E_);
    float4* dst = (float4*)(x0 + (size_t)row * E_);
    dst[threadIdx.x] = src[threadIdx.x];
}

// ---------------------------------------------------------------- bidirectional LSTM layer
// Persistent, 256 blocks (1/CU), 512 threads (2 waves/SIMD) — r13 config,
// the proven optimum: r14 showed 4 waves/SIMD regresses (barrier cost x16
// waves, only 2 EG chunks between syncs, 2x bank conflicts); l0==l1 time
// proves the kernel is sync-chain-bound, not throughput-bound.
// Protocol: flags + WT h-stores; publish at M-end (max slack, r12 lesson)
// with the ack covered by the x(t+1)h1 GLL issue; poll after first E phase;
// column-half h staging (1 flag/thread). All staging via global_load_lds;
// NO cross-phase register arrays (r4-r6/r9: scratch -> 10GB HBM writes).
#define GLL_TILE(DST, SRC, RS)                                      \
    _Pragma("unroll")                                               \
    for (int k = 0; k < 4; ++k) {                                   \
        const int m_  = (wvi << 2) | k;                             \
        const int rr_ = m_ >> 1;                                    \
        const int ch_ = (m_ & 1) << 8;                              \
        gll16((SRC) + (size_t)rr_ * (RS) + ch_ + lane * 4,          \
              (DST) + rr_ * 516 + ch_);                             \
    }

// h tile: wave w loads rows 4(w&3)..+3 of column-half (w>>2)
#define GLL_TILE_H(DST, SRC, RS)                                    \
    _Pragma("unroll")                                               \
    for (int k = 0; k < 4; ++k) {                                   \
        const int rr_ = ((wvi & 3) << 2) | k;                       \
        const int ch_ = (wvi >> 2) << 8;                            \
        gll16((SRC) + (size_t)rr_ * (RS) + ch_ + lane * 4,          \
              (DST) + rr_ * 516 + ch_);                             \
    }

// CN-chunk slice of the 4x4-microtile GEMM over a 512-wide LDS tile
#define EG(PP, WEXPR, CB, CN)                                                 \
    _Pragma("unroll")                                                         \
    for (int cc = (CB); cc < (CB) + (CN); ++cc) {                             \
        const int scol = kb + (((cc + ks) & 3) << 2);                         \
        const float4 hv0 = *(const float4*)&(PP)[(b40 + 0) * 516 + scol];     \
        const float4 hv1 = *(const float4*)&(PP)[(b40 + 1) * 516 + scol];     \
        const float4 hv2 = *(const float4*)&(PP)[(b40 + 2) * 516 + scol];     \
        const float4 hv3 = *(const float4*)&(PP)[(b40 + 3) * 516 + scol];     \
        _Pragma("unroll")                                                     \
        for (int j = 0; j < 4; ++j) {                                         \
            const float4 wv = (WEXPR);                                        \
            acc[j*4+0] = fmaf(wv.x, hv0.x, acc[j*4+0]);                       \
            acc[j*4+0] = fmaf(wv.y, hv0.y, acc[j*4+0]);                       \
            acc[j*4+0] = fmaf(wv.z, hv0.z, acc[j*4+0]);                       \
            acc[j*4+0] = fmaf(wv.w, hv0.w, acc[j*4+0]);                       \
            acc[j*4+1] = fmaf(wv.x, hv1.x, acc[j*4+1]);                       \
            acc[j*4+1] = fmaf(wv.y, hv1.y, acc[j*4+1]);                       \
            acc[j*4+1] = fmaf(wv.z, hv1.z, acc[j*4+1]);                       \
            acc[j*4+1] = fmaf(wv.w, hv1.w, acc[j*4+1]);                       \
            acc[j*4+2] = fmaf(wv.x, hv2.x, acc[j*4+2]);                       \
            acc[j*4+2] = fmaf(wv.y, hv2.y, acc[j*4+2]);                       \
            acc[j*4+2] = fmaf(wv.z, hv2.z, acc[j*4+2]);                       \
            acc[j*4+2] = fmaf(wv.w, hv2.w, acc[j*4+2]);                       \
            acc[j*4+3] = fmaf(wv.x, hv3.x, acc[j*4+3]);                       \
            acc[j*4+3] = fmaf(wv.y, hv3.y, acc[j*4+3]);                       \
            acc[j*4+3] = fmaf(wv.z, hv3.z, acc[j*4+3]);                       \
            acc[j*4+3] = fmaf(wv.w, hv3.w, acc[j*4+3]);                       \
        }                                                                     \
    }

// poll: 1 flag/thread; wave covers the 64 producers of its column half
#define POLL1()                                                               \
    do {                                                                      \
        int* fp_ = &flags[(dir << 7) + ((wvi >> 2) << 6) + (tid & 63)];       \
        while (__hip_atomic_load(fp_, __ATOMIC_RELAXED,                       \
                                 __HIP_MEMORY_SCOPE_AGENT) < step) { }        \
        asm volatile("" ::: "memory");                                        \
    } while (0)

template<int DIN>
__global__ __launch_bounds__(512, 2) void lstm_bidir(
    const float* __restrict__ x,
    const float* __restrict__ wihF, const float* __restrict__ whhF,
    const float* __restrict__ bihF, const float* __restrict__ bhhF,
    const float* __restrict__ wihR, const float* __restrict__ whhR,
    const float* __restrict__ bihR, const float* __restrict__ bhhR,
    float* __restrict__ hs,          // (B, S, 1024): [0:512]=fwd, [512:1024]=rev
    int* __restrict__ flags)         // 256 ints, flags[bid]
{
    constexpr int NH = DIN / 512;    // 1 (l0) or 2 (l1)

    const int tid = threadIdx.x;
    const int bid = blockIdx.x;
    const int dir = bid >> 7;
    const int c0  = (bid & 127) << 2;

    const float* wih = dir ? wihR : wihF;
    const float* whh = dir ? whhR : whhF;
    const float* bih = dir ? bihR : bihF;
    const float* bhh = dir ? bhhR : bhhF;

    __shared__ __align__(16) float s_wih[16 * 516];   // W_ih cols 0..511
    __shared__ __align__(16) float s_whh[16 * 516];
    __shared__ __align__(16) float s_P[16 * 516];
    __shared__ __align__(16) float s_Q[16 * 516];
    __shared__ __align__(16) float s_red[8][16][20];
    __shared__ float s_bias[16];

    for (int r = 0; r < 16; ++r) {
        const int grow = ((r >> 2) * H_) + c0 + (r & 3);
        const float* srcI = wih + (size_t)grow * DIN;
        for (int i = tid; i < 128; i += 512)
            *(float4*)&s_wih[r * 516 + i * 4] = *(const float4*)&srcI[i * 4];
        const float* srcH = whh + (size_t)grow * H_;
        for (int i = tid; i < 128; i += 512)
            *(float4*)&s_whh[r * 516 + i * 4] = *(const float4*)&srcH[i * 4];
    }
    if (tid < 16) {
        const int grow = ((tid >> 2) * H_) + c0 + (tid & 3);
        s_bias[tid] = bih[grow] + bhh[grow];
    }

    const int rb   = tid & 15;
    const int ks   = tid >> 4;        // k-slice 0..31 (16 cols each)
    const int r40  = (rb >> 2) << 2;
    const int b40  = (rb & 3) << 2;
    const int kb   = ks << 4;
    const int lane = tid & 63;
    const int wvi  = tid >> 6;        // wave 0..7

    float cstate = 0.0f;              // meaningful for tid<64
    float acc[16];

    {   // prologue: stage x(t0)
        const int t0 = dir ? (S_ - 1) : 0;
        GLL_TILE(s_P, x + (size_t)t0 * DIN, (size_t)S_ * DIN);
        if (NH == 2) GLL_TILE(s_Q, x + (size_t)t0 * DIN + 512, (size_t)S_ * DIN);
    }

    for (int step = 0; step < S_; ++step) {
        const int t  = dir ? (S_ - 1 - step) : step;
        const int sn = (step + 1 < S_) ? (step + 1) : (S_ - 1);
        const int tn = dir ? (S_ - 1 - sn) : sn;
        const int tp = dir ? (t + 1) : (t - 1);

        // ---- top: drain own GLL x prefetch
        WAITV0();
        BAR();

        #pragma unroll
        for (int a = 0; a < 16; ++a) acc[a] = 0.0f;

        if constexpr (NH == 2) {
            // E1: x(t) half1 (Q) x W_ih[:,512:] streamed from L2/L1
            EG(s_Q, (*(const float4*)&wih[(size_t)((r40 >> 2) * H_ + c0 + j) * DIN + 512 + scol]), 0, 4);
            BAR();                        // Q consumed by all waves
            if (step > 0) {               // flag propagated during E1
                POLL1();
                GLL_TILE_H(s_Q, hs + (size_t)tp * 1024 + dir * 512, (size_t)S_ * 1024);
            }
            // E0: x(t) half0 (P) x LDS W_ih -- h DMA flies under it
            EG(s_P, (*(const float4*)&s_wih[(r40 + j) * 516 + scol]), 0, 4);
        } else {
            // E_a: first half of x-part (flag propagates during it)
            EG(s_P, (*(const float4*)&s_wih[(r40 + j) * 516 + scol]), 0, 2);
            if (step > 0) {
                POLL1();
                GLL_TILE_H(s_Q, hs + (size_t)tp * 1024 + dir * 512, (size_t)S_ * 1024);
            }
            // E_b: second half hides the h DMA
            EG(s_P, (*(const float4*)&s_wih[(r40 + j) * 516 + scol]), 2, 2);
        }

        WAITV0();                         // own h-GLL share landed
        BAR();                            // all waves' shares landed; P free

        GLL_TILE(s_P, x + (size_t)tn * DIN, (size_t)S_ * DIN);   // x(t+1) h0

        if (step > 0) {                   // J: gates += h @ W_hh^T
            EG(s_Q, (*(const float4*)&s_whh[(r40 + j) * 516 + scol]), 0, 4);
        }

        // K: reduce 4 in-wave k-slices, then 8 wave partials via s_red
        #pragma unroll
        for (int a = 0; a < 16; ++a) {
            float v = acc[a];
            v += __shfl_xor(v, 16);
            v += __shfl_xor(v, 32);
            acc[a] = v;
        }
        if ((tid & 63) < 16) {
            float* base = &s_red[wvi][tid & 15][0];
            #pragma unroll
            for (int q = 0; q < 4; ++q)
                *(float4*)&base[q * 4] =
                    make_float4(acc[q * 4 + 0], acc[q * 4 + 1], acc[q * 4 + 2], acc[q * 4 + 3]);
        }
        BAR();                            // s_red ready; Q free

        // M: cell update + WT store (wave 0; ack covered by GLL_Q issue)
        if (tid < 64) {
            const int c = tid >> 4, b = tid & 15;
            float g[4];
            #pragma unroll
            for (int gg = 0; gg < 4; ++gg) {
                const int rbv = (gg << 2) | (b >> 2);
                const int av  = (c << 2) | (b & 3);
                float s = s_bias[gg * 4 + c];
                #pragma unroll
                for (int w = 0; w < 8; ++w) s += s_red[w][rbv][av];
                g[gg] = s;
            }
            const float iv = fsig_(g[0]);
            const float fv = fsig_(g[1]);
            const float gv = ftanh_(g[2]);
            const float ov = fsig_(g[3]);
            cstate = fv * cstate + iv * gv;
            const float hval = ov * ftanh_(cstate);
            f4_t o;                          // gather 4 cells of one batch
            o.x = hval;
            o.y = __shfl(hval, tid + 16);
            o.z = __shfl(hval, tid + 32);
            o.w = __shfl(hval, tid + 48);
            if (tid < 16)
                store_wt4(&hs[(size_t)(b * S_ + t) * 1024 + dir * 512 + c0], o);
        }
        if constexpr (NH == 2)            // issue BEFORE the ack wait: covers it
            GLL_TILE(s_Q, x + (size_t)tn * DIN + 512, (size_t)S_ * DIN);
        if (tid < 64) {
            if (NH == 2) { WAITV4(); }    // drains only the older WT stores
            else         { WAITV0(); }
            if (tid == 0)                 // publish h(t): M-end, max slack
                __hip_atomic_store(&flags[bid], step + 1,
                                   __ATOMIC_RELAXED, __HIP_MEMORY_SCOPE_AGENT);
        }
    }
}

// ---------------------------------------------------------------- out proj + argmax -> mask
__global__ __launch_bounds__(256) void outproj_kernel(
    const float* __restrict__ x1, const float* __restrict__ out_w,
    const float* __restrict__ out_b, float* __restrict__ res,
    unsigned char* __restrict__ mask)
{
    const int tid  = threadIdx.x;
    const int lane = tid & 63;
    const int w    = tid >> 6;
    const int row  = blockIdx.x * 4 + w;     // b*S + s
    const float* xr = x1 + (size_t)row * 1024;
    float4 xv[4];
    #pragma unroll
    for (int i = 0; i < 4; ++i) xv[i] = *(const float4*)&xr[(i * 64 + lane) << 2];
    float best = -__builtin_inff();
    int bi = 0;
    #pragma unroll
    for (int l = 0; l < L_; ++l) {
        const float* wr = out_w + l * 1024;
        float s = 0.0f;
        #pragma unroll
        for (int i = 0; i < 4; ++i) {
            const float4 wv = *(const float4*)&wr[(i * 64 + lane) << 2];
            s = fmaf(xv[i].x, wv.x, s);
            s = fmaf(xv[i].y, wv.y, s);
            s = fmaf(xv[i].z, wv.z, s);
            s = fmaf(xv[i].w, wv.w, s);
        }
        #pragma unroll
        for (int d = 32; d >= 1; d >>= 1) s += __shfl_xor(s, d);
        s += out_b[l];
        if (lane == l) res[(size_t)row * L_ + l] = s;
        if (s > best) { best = s; bi = l; }     // strict > keeps first index (jnp.argmax)
    }
    if (lane == 0) mask[row] = (unsigned char)(bi != 0);
}

// ---------------------------------------------------------------- batched fp32 GEMM 128x128x8
// 256 threads, 8x8 microtile: 64 FMA per 4 ds_read_b128 per k (4x the
// FMA:LDS ratio of the old 64x64 tile, which was LDS-issue-bound).
// MODE 0: C = A @ B^T ; MODE 1: C = A @ B + D
template<int MODE>
__global__ __launch_bounds__(256) void gemm128(
    const float* __restrict__ A, const float* __restrict__ Bm,
    const float* __restrict__ D, float* __restrict__ C,
    const int M, const int N, const int K)
{
    const int bz = blockIdx.z;
    const float* Ab = A  + (size_t)bz * M * K;
    const float* Bb = Bm + (size_t)bz * N * K;
    const float* Db = (MODE == 1) ? (D + (size_t)bz * M * N) : (const float*)nullptr;
    float* Cb = C + (size_t)bz * M * N;
    const int m0 = blockIdx.y << 7;
    const int n0 = blockIdx.x << 7;
    const int tid = threadIdx.x;
    const int tm = tid >> 4, tn = tid & 15;      // 16x16 threads, 8x8 micro
    const int am = tid >> 1, ak = (tid & 1) << 2;   // A/B^T load: 128 rows x 8 cols
    const int bk1 = tid >> 5, bn1 = (tid & 31) << 2; // B (K,N) load: 8 rows x 128 cols
    __shared__ float As[8][132];
    __shared__ float Bs[8][132];
    float acc[8][8] = {};
    for (int k0 = 0; k0 < K; k0 += 8) {
        const float4 av = *(const float4*)&Ab[(size_t)(m0 + am) * K + k0 + ak];
        float4 bv;
        if (MODE == 0) bv = *(const float4*)&Bb[(size_t)(n0 + am) * K + k0 + ak];
        else           bv = *(const float4*)&Bb[(size_t)(k0 + bk1) * N + n0 + bn1];
        __syncthreads();
        As[ak + 0][am] = av.x; As[ak + 1][am] = av.y;
        As[ak + 2][am] = av.z; As[ak + 3][am] = av.w;
        if (MODE == 0) {
            Bs[ak + 0][am] = bv.x; Bs[ak + 1][am] = bv.y;
            Bs[ak + 2][am] = bv.z; Bs[ak + 3][am] = bv.w;
        } else {
            *(float4*)&Bs[bk1][bn1] = bv;
        }
        __syncthreads();
        #pragma unroll
        for (int k = 0; k < 8; ++k) {
            const float4 a0 = *(const float4*)&As[k][tm << 3];
            const float4 a1 = *(const float4*)&As[k][(tm << 3) + 4];
            const float4 b0 = *(const float4*)&Bs[k][tn << 3];
            const float4 b1 = *(const float4*)&Bs[k][(tn << 3) + 4];
            const float aa[8] = {a0.x, a0.y, a0.z, a0.w, a1.x, a1.y, a1.z, a1.w};
            const float bb[8] = {b0.x, b0.y, b0.z, b0.w, b1.x, b1.y, b1.z, b1.w};
            #pragma unroll
            for (int i = 0; i < 8; ++i)
                #pragma unroll
                for (int j = 0; j < 8; ++j)
                    acc[i][j] = fmaf(aa[i], bb[j], acc[i][j]);
        }
    }
    #pragma unroll
    for (int i = 0; i < 8; ++i) {
        const size_t ci = (size_t)(m0 + (tm << 3) + i) * N + n0 + (tn << 3);
        float4 o0 = make_float4(acc[i][0], acc[i][1], acc[i][2], acc[i][3]);
        float4 o1 = make_float4(acc[i][4], acc[i][5], acc[i][6], acc[i][7]);
        if (MODE == 1) {
            const float4 d0 = *(const float4*)&Db[ci];
            const float4 d1 = *(const float4*)&Db[ci + 4];
            o0.x += d0.x; o0.y += d0.y; o0.z += d0.z; o0.w += d0.w;
            o1.x += d1.x; o1.y += d1.y; o1.z += d1.z; o1.w += d1.w;
        }
        *(float4*)&Cb[ci] = o0;
        *(float4*)&Cb[ci + 4] = o1;
    }
}

// ---------------------------------------------------------------- dual masked softmax (in place)
__global__ __launch_bounds__(256) void softmax_kernel(float* __restrict__ sc,
                                                      const unsigned char* __restrict__ mask)
{
    const float INF = __builtin_inff();
    const int row = blockIdx.x;          // b*S + s
    const int b = row >> 10;
    float* pr = sc + (size_t)row * 1024;
    const unsigned char* mr = mask + b * 1024;
    const int tid = threadIdx.x;
    const int lane = tid & 63;
    const int w = tid >> 6;
    const int j0 = tid << 2;
    const float4 v = *(const float4*)&pr[j0];
    const unsigned mu = *(const unsigned*)&mr[j0];
    const bool m0 = (mu & 0xffu) != 0, m1 = ((mu >> 8) & 0xffu) != 0;
    const bool m2 = ((mu >> 16) & 0xffu) != 0, m3 = ((mu >> 24) & 0xffu) != 0;

    float mme = -INF, mot = -INF;
    if (m0) mme = fmaxf(mme, v.x); else mot = fmaxf(mot, v.x);
    if (m1) mme = fmaxf(mme, v.y); else mot = fmaxf(mot, v.y);
    if (m2) mme = fmaxf(mme, v.z); else mot = fmaxf(mot, v.z);
    if (m3) mme = fmaxf(mme, v.w); else mot = fmaxf(mot, v.w);
    #pragma unroll
    for (int d = 32; d >= 1; d >>= 1) {
        mme = fmaxf(mme, __shfl_xor(mme, d));
        mot = fmaxf(mot, __shfl_xor(mot, d));
    }
    __shared__ float sm[2][4];
    if (lane == 0) { sm[0][w] = mme; sm[1][w] = mot; }
    __syncthreads();
    float Mme = fmaxf(fmaxf(sm[0][0], sm[0][1]), fmaxf(sm[0][2], sm[0][3]));
    float Mot = fmaxf(fmaxf(sm[1][0], sm[1][1]), fmaxf(sm[1][2], sm[1][3]));
    const float MmeU = (Mme == -INF) ? 0.0f : Mme;
    const float MotU = (Mot == -INF) ? 0.0f : Mot;

    const float e0 = expf(v.x - (m0 ? MmeU : MotU));
    const float e1 = expf(v.y - (m1 ? MmeU : MotU));
    const float e2 = expf(v.z - (m2 ? MmeU : MotU));
    const float e3 = expf(v.w - (m3 ? MmeU : MotU));
    float sme = 0.0f, sot = 0.0f;
    if (m0) sme += e0; else sot += e0;
    if (m1) sme += e1; else sot += e1;
    if (m2) sme += e2; else sot += e2;
    if (m3) sme += e3; else sot += e3;
    #pragma unroll
    for (int d = 32; d >= 1; d >>= 1) {
        sme += __shfl_xor(sme, d);
        sot += __shfl_xor(sot, d);
    }
    __syncthreads();
    if (lane == 0) { sm[0][w] = sme; sm[1][w] = sot; }
    __syncthreads();
    const float Dme = sm[0][0] + sm[0][1] + sm[0][2] + sm[0][3];
    const float Dot = sm[1][0] + sm[1][1] + sm[1][2] + sm[1][3];

    float4 o;
    o.x = m0 ? (Dme > 0.0f ? e0 / Dme : 0.0f) : (Dot > 0.0f ? e0 / Dot : 0.0f);
    o.y = m1 ? (Dme > 0.0f ? e1 / Dme : 0.0f) : (Dot > 0.0f ? e1 / Dot : 0.0f);
    o.z = m2 ? (Dme > 0.0f ? e2 / Dme : 0.0f) : (Dot > 0.0f ? e2 / Dot : 0.0f);
    o.w = m3 ? (Dme > 0.0f ? e3 / Dme : 0.0f) : (Dot > 0.0f ? e3 / Dot : 0.0f);
    *(float4*)&pr[j0] = o;
}

// ---------------------------------------------------------------- launch
extern "C" void kernel_launch(void* const* d_in, const int* in_sizes, int n_in,
                              void* d_out, int out_size, void* d_ws, size_t ws_size,
                              hipStream_t stream)
{
    const float* emb     = (const float*)d_in[0];
    const float* wih_l0  = (const float*)d_in[1];
    const float* whh_l0  = (const float*)d_in[2];
    const float* bih_l0  = (const float*)d_in[3];
    const float* bhh_l0  = (const float*)d_in[4];
    const float* wih_l0r = (const float*)d_in[5];
    const float* whh_l0r = (const float*)d_in[6];
    const float* bih_l0r = (const float*)d_in[7];
    const float* bhh_l0r = (const float*)d_in[8];
    const float* wih_l1  = (const float*)d_in[9];
    const float* whh_l1  = (const float*)d_in[10];
    const float* bih_l1  = (const float*)d_in[11];
    const float* bhh_l1  = (const float*)d_in[12];
    const float* wih_l1r = (const float*)d_in[13];
    const float* whh_l1r = (const float*)d_in[14];
    const float* bih_l1r = (const float*)d_in[15];
    const float* bhh_l1r = (const float*)d_in[16];
    const float* out_w   = (const float*)d_in[17];
    const float* out_b   = (const float*)d_in[18];
    const int*   tokens  = (const int*)d_in[19];

    float* out     = (float*)d_out;
    float* A_out   = out;                          // (16,1024,1024)
    float* res_out = out + 16777216;               // (16,1024,10)

    float* ws = (float*)d_ws;
    float* x0 = ws;                                //  8,388,608 f
    float* h0 = ws + 8388608;                      // 16,777,216 f
    float* x1 = h0 + 16777216;                     // 16,777,216 f
    float* sc = x1 + 16777216;                     // 16,777,216 f (scores, then P in place)
    unsigned char* mask = (unsigned char*)(sc + 16777216);   // 16,384 B
    int* flags0 = (int*)(mask + 16384);            // 256 ints
    int* flags1 = flags0 + 256;

    (void)in_sizes; (void)n_in; (void)out_size; (void)ws_size;

    (void)hipMemsetAsync(flags0, 0, 512 * sizeof(int), stream);

    embed_kernel<<<B_ * S_, 128, 0, stream>>>(tokens, emb, x0);

    lstm_bidir<512><<<256, 512, 0, stream>>>(
        x0, wih_l0, whh_l0, bih_l0, bhh_l0,
        wih_l0r, whh_l0r, bih_l0r, bhh_l0r, h0, flags0);

    lstm_bidir<1024><<<256, 512, 0, stream>>>(
        h0, wih_l1, whh_l1, bih_l1, bhh_l1,
        wih_l1r, whh_l1r, bih_l1r, bhh_l1r, x1, flags1);

    outproj_kernel<<<(B_ * S_) / 4, 256, 0, stream>>>(x1, out_w, out_b, res_out, mask);

    dim3 gg(8, 8, 16);
    gemm128<0><<<gg, 256, 0, stream>>>(x1, x1, nullptr, sc, 1024, 1024, 1024);

    softmax_kernel<<<B_ * S_, 256, 0, stream>>>(sc, mask);

    gemm128<1><<<gg, 256, 0, stream>>>(sc, x1, x1, A_out, 1024, 1024, 1024);
}

// Round 16
// 12525.956 us; speedup vs baseline: 1.1291x; 1.0062x over previous
//
#include <hip/hip_runtime.h>

#define B_ 16
#define S_ 1024
#define H_ 512
#define E_ 512
#define L_ 10

typedef float f4_t __attribute__((ext_vector_type(4)));
typedef __attribute__((address_space(1))) void gas_void;
typedef __attribute__((address_space(3))) void las_void;

__device__ __forceinline__ float frcp_(float x)
{
    float r;
    asm("v_rcp_f32 %0, %1" : "=v"(r) : "v"(x));
    return r;
}
__device__ __forceinline__ float fsig_(float x) { return frcp_(1.0f + __expf(-x)); }
__device__ __forceinline__ float ftanh_(float x)
{
    const float e = __expf(-2.0f * fabsf(x));
    const float r = (1.0f - e) * frcp_(1.0f + e);
    return copysignf(r, x);
}

// Write-through store: bypasses L1/L2 (sc0 sc1), lands at LLC once acked.
__device__ __forceinline__ void store_wt4(float* p, f4_t v)
{
    asm volatile("global_store_dwordx4 %0, %1, off sc0 sc1" :: "v"(p), "v"(v) : "memory");
}

// Async global->LDS DMA: per-lane global src, wave-uniform LDS base + lane*16.
__device__ __forceinline__ void gll16(const float* g, float* l)
{
    __builtin_amdgcn_global_load_lds((const gas_void*)g, (las_void*)l, 16, 0, 0);
}

#define WAITV0() asm volatile("s_waitcnt vmcnt(0)" ::: "memory")
#define WAITV4() asm volatile("s_waitcnt vmcnt(4)" ::: "memory")
// raw barrier: drains LDS ops only, keeps GLL/global prefetches in flight
#define BAR() do { asm volatile("s_waitcnt lgkmcnt(0)" ::: "memory"); \
                   __builtin_amdgcn_s_barrier(); } while (0)

// ---------------------------------------------------------------- embedding
__global__ __launch_bounds__(128) void embed_kernel(const int* __restrict__ tokens,
                                                    const float* __restrict__ emb,
                                                    float* __restrict__ x0)
{
    const int row = blockIdx.x;              // b*S + s
    const int tok = tokens[row];
    const float4* src = (const float4*)(emb + (size_t)tok * E_);
    float4* dst = (float4*)(x0 + (size_t)row * E_);
    dst[threadIdx.x] = src[threadIdx.x];
}

// ---------------------------------------------------------------- bidirectional LSTM layer
// Persistent, 256 blocks (1/CU), 512 threads (2 waves/SIMD) — r13/r15
// config. r16 change: SINGLE-WAVE POLLING. Previously all 512 threads spun
// on uncached flag loads (131K concurrent LLC reads chip-wide) contending
// with the WT h-stores / flag stores being waited on (r9 lesson in
// miniature; r10's flag-packing already showed poll traffic in FETCH_SIZE).
// Now wave 7 alone polls all 128 producer flags (2/lane), then a raw
// barrier releases all waves to issue their h-GLL shares. Poll traffic /8.
// Protocol otherwise r13: publish at M-end (max slack, r12), ack covered
// by the x(t+1)h1 GLL issue, column-half h staging. All staging via
// global_load_lds; NO cross-phase register arrays (r4-r6/r9 lesson).
#define GLL_TILE(DST, SRC, RS)                                      \
    _Pragma("unroll")                                               \
    for (int k = 0; k < 4; ++k) {                                   \
        const int m_  = (wvi << 2) | k;                             \
        const int rr_ = m_ >> 1;                                    \
        const int ch_ = (m_ & 1) << 8;                              \
        gll16((SRC) + (size_t)rr_ * (RS) + ch_ + lane * 4,          \
              (DST) + rr_ * 516 + ch_);                             \
    }

// h tile: wave w loads rows 4(w&3)..+3 of column-half (w>>2)
#define GLL_TILE_H(DST, SRC, RS)                                    \
    _Pragma("unroll")                                               \
    for (int k = 0; k < 4; ++k) {                                   \
        const int rr_ = ((wvi & 3) << 2) | k;                       \
        const int ch_ = (wvi >> 2) << 8;                            \
        gll16((SRC) + (size_t)rr_ * (RS) + ch_ + lane * 4,          \
              (DST) + rr_ * 516 + ch_);                             \
    }

// CN-chunk slice of the 4x4-microtile GEMM over a 512-wide LDS tile
#define EG(PP, WEXPR, CB, CN)                                                 \
    _Pragma("unroll")                                                         \
    for (int cc = (CB); cc < (CB) + (CN); ++cc) {                             \
        const int scol = kb + (((cc + ks) & 3) << 2);                         \
        const float4 hv0 = *(const float4*)&(PP)[(b40 + 0) * 516 + scol];     \
        const float4 hv1 = *(const float4*)&(PP)[(b40 + 1) * 516 + scol];     \
        const float4 hv2 = *(const float4*)&(PP)[(b40 + 2) * 516 + scol];     \
        const float4 hv3 = *(const float4*)&(PP)[(b40 + 3) * 516 + scol];     \
        _Pragma("unroll")                                                     \
        for (int j = 0; j < 4; ++j) {                                         \
            const float4 wv = (WEXPR);                                        \
            acc[j*4+0] = fmaf(wv.x, hv0.x, acc[j*4+0]);                       \
            acc[j*4+0] = fmaf(wv.y, hv0.y, acc[j*4+0]);                       \
            acc[j*4+0] = fmaf(wv.z, hv0.z, acc[j*4+0]);                       \
            acc[j*4+0] = fmaf(wv.w, hv0.w, acc[j*4+0]);                       \
            acc[j*4+1] = fmaf(wv.x, hv1.x, acc[j*4+1]);                       \
            acc[j*4+1] = fmaf(wv.y, hv1.y, acc[j*4+1]);                       \
            acc[j*4+1] = fmaf(wv.z, hv1.z, acc[j*4+1]);                       \
            acc[j*4+1] = fmaf(wv.w, hv1.w, acc[j*4+1]);                       \
            acc[j*4+2] = fmaf(wv.x, hv2.x, acc[j*4+2]);                       \
            acc[j*4+2] = fmaf(wv.y, hv2.y, acc[j*4+2]);                       \
            acc[j*4+2] = fmaf(wv.z, hv2.z, acc[j*4+2]);                       \
            acc[j*4+2] = fmaf(wv.w, hv2.w, acc[j*4+2]);                       \
            acc[j*4+3] = fmaf(wv.x, hv3.x, acc[j*4+3]);                       \
            acc[j*4+3] = fmaf(wv.y, hv3.y, acc[j*4+3]);                       \
            acc[j*4+3] = fmaf(wv.z, hv3.z, acc[j*4+3]);                       \
            acc[j*4+3] = fmaf(wv.w, hv3.w, acc[j*4+3]);                       \
        }                                                                     \
    }

// single-wave poll: wave 7's 64 lanes cover all 128 producers (2 flags/lane)
#define POLLW()                                                               \
    do {                                                                      \
        int* fp0_ = &flags[(dir << 7) + lane];                                \
        int* fp1_ = fp0_ + 64;                                                \
        while (__hip_atomic_load(fp0_, __ATOMIC_RELAXED,                      \
                                 __HIP_MEMORY_SCOPE_AGENT) < step ||          \
               __hip_atomic_load(fp1_, __ATOMIC_RELAXED,                      \
                                 __HIP_MEMORY_SCOPE_AGENT) < step) { }        \
        asm volatile("" ::: "memory");                                        \
    } while (0)

template<int DIN>
__global__ __launch_bounds__(512, 2) void lstm_bidir(
    const float* __restrict__ x,
    const float* __restrict__ wihF, const float* __restrict__ whhF,
    const float* __restrict__ bihF, const float* __restrict__ bhhF,
    const float* __restrict__ wihR, const float* __restrict__ whhR,
    const float* __restrict__ bihR, const float* __restrict__ bhhR,
    float* __restrict__ hs,          // (B, S, 1024): [0:512]=fwd, [512:1024]=rev
    int* __restrict__ flags)         // 256 ints, flags[bid]
{
    constexpr int NH = DIN / 512;    // 1 (l0) or 2 (l1)

    const int tid = threadIdx.x;
    const int bid = blockIdx.x;
    const int dir = bid >> 7;
    const int c0  = (bid & 127) << 2;

    const float* wih = dir ? wihR : wihF;
    const float* whh = dir ? whhR : whhF;
    const float* bih = dir ? bihR : bihF;
    const float* bhh = dir ? bhhR : bhhF;

    __shared__ __align__(16) float s_wih[16 * 516];   // W_ih cols 0..511
    __shared__ __align__(16) float s_whh[16 * 516];
    __shared__ __align__(16) float s_P[16 * 516];
    __shared__ __align__(16) float s_Q[16 * 516];
    __shared__ __align__(16) float s_red[8][16][20];
    __shared__ float s_bias[16];

    for (int r = 0; r < 16; ++r) {
        const int grow = ((r >> 2) * H_) + c0 + (r & 3);
        const float* srcI = wih + (size_t)grow * DIN;
        for (int i = tid; i < 128; i += 512)
            *(float4*)&s_wih[r * 516 + i * 4] = *(const float4*)&srcI[i * 4];
        const float* srcH = whh + (size_t)grow * H_;
        for (int i = tid; i < 128; i += 512)
            *(float4*)&s_whh[r * 516 + i * 4] = *(const float4*)&srcH[i * 4];
    }
    if (tid < 16) {
        const int grow = ((tid >> 2) * H_) + c0 + (tid & 3);
        s_bias[tid] = bih[grow] + bhh[grow];
    }

    const int rb   = tid & 15;
    const int ks   = tid >> 4;        // k-slice 0..31 (16 cols each)
    const int r40  = (rb >> 2) << 2;
    const int b40  = (rb & 3) << 2;
    const int kb   = ks << 4;
    const int lane = tid & 63;
    const int wvi  = tid >> 6;        // wave 0..7

    float cstate = 0.0f;              // meaningful for tid<64
    float acc[16];

    {   // prologue: stage x(t0)
        const int t0 = dir ? (S_ - 1) : 0;
        GLL_TILE(s_P, x + (size_t)t0 * DIN, (size_t)S_ * DIN);
        if (NH == 2) GLL_TILE(s_Q, x + (size_t)t0 * DIN + 512, (size_t)S_ * DIN);
    }

    for (int step = 0; step < S_; ++step) {
        const int t  = dir ? (S_ - 1 - step) : step;
        const int sn = (step + 1 < S_) ? (step + 1) : (S_ - 1);
        const int tn = dir ? (S_ - 1 - sn) : sn;
        const int tp = dir ? (t + 1) : (t - 1);

        // ---- top: drain own GLL x prefetch
        WAITV0();
        BAR();

        #pragma unroll
        for (int a = 0; a < 16; ++a) acc[a] = 0.0f;

        if constexpr (NH == 2) {
            // E1: x(t) half1 (Q) x W_ih[:,512:] streamed from L2/L1
            EG(s_Q, (*(const float4*)&wih[(size_t)((r40 >> 2) * H_ + c0 + j) * DIN + 512 + scol]), 0, 4);
            BAR();                        // Q consumed by all waves
            if (step > 0) {               // flag propagated during E1
                if (wvi == 7) POLLW();
                BAR();                    // flags seen -> all waves may fetch h
                GLL_TILE_H(s_Q, hs + (size_t)tp * 1024 + dir * 512, (size_t)S_ * 1024);
            }
            // E0: x(t) half0 (P) x LDS W_ih -- h DMA flies under it
            EG(s_P, (*(const float4*)&s_wih[(r40 + j) * 516 + scol]), 0, 4);
        } else {
            // E_a: first half of x-part (flag propagates during it)
            EG(s_P, (*(const float4*)&s_wih[(r40 + j) * 516 + scol]), 0, 2);
            if (step > 0) {
                if (wvi == 7) POLLW();
                BAR();                    // flags seen -> all waves may fetch h
                GLL_TILE_H(s_Q, hs + (size_t)tp * 1024 + dir * 512, (size_t)S_ * 1024);
            }
            // E_b: second half hides the h DMA
            EG(s_P, (*(const float4*)&s_wih[(r40 + j) * 516 + scol]), 2, 2);
        }

        WAITV0();                         // own h-GLL share landed
        BAR();                            // all waves' shares landed; P free

        GLL_TILE(s_P, x + (size_t)tn * DIN, (size_t)S_ * DIN);   // x(t+1) h0

        if (step > 0) {                   // J: gates += h @ W_hh^T
            EG(s_Q, (*(const float4*)&s_whh[(r40 + j) * 516 + scol]), 0, 4);
        }

        // K: reduce 4 in-wave k-slices, then 8 wave partials via s_red
        #pragma unroll
        for (int a = 0; a < 16; ++a) {
            float v = acc[a];
            v += __shfl_xor(v, 16);
            v += __shfl_xor(v, 32);
            acc[a] = v;
        }
        if ((tid & 63) < 16) {
            float* base = &s_red[wvi][tid & 15][0];
            #pragma unroll
            for (int q = 0; q < 4; ++q)
                *(float4*)&base[q * 4] =
                    make_float4(acc[q * 4 + 0], acc[q * 4 + 1], acc[q * 4 + 2], acc[q * 4 + 3]);
        }
        BAR();                            // s_red ready; Q free

        // M: cell update + WT store (wave 0; ack covered by GLL_Q issue)
        if (tid < 64) {
            const int c = tid >> 4, b = tid & 15;
            float g[4];
            #pragma unroll
            for (int gg = 0; gg < 4; ++gg) {
                const int rbv = (gg << 2) | (b >> 2);
                const int av  = (c << 2) | (b & 3);
                float s = s_bias[gg * 4 + c];
                #pragma unroll
                for (int w = 0; w < 8; ++w) s += s_red[w][rbv][av];
                g[gg] = s;
            }
            const float iv = fsig_(g[0]);
            const float fv = fsig_(g[1]);
            const float gv = ftanh_(g[2]);
            const float ov = fsig_(g[3]);
            cstate = fv * cstate + iv * gv;
            const float hval = ov * ftanh_(cstate);
            f4_t o;                          // gather 4 cells of one batch
            o.x = hval;
            o.y = __shfl(hval, tid + 16);
            o.z = __shfl(hval, tid + 32);
            o.w = __shfl(hval, tid + 48);
            if (tid < 16)
                store_wt4(&hs[(size_t)(b * S_ + t) * 1024 + dir * 512 + c0], o);
        }
        if constexpr (NH == 2)            // issue BEFORE the ack wait: covers it
            GLL_TILE(s_Q, x + (size_t)tn * DIN + 512, (size_t)S_ * DIN);
        if (tid < 64) {
            if (NH == 2) { WAITV4(); }    // drains only the older WT stores
            else         { WAITV0(); }
            if (tid == 0)                 // publish h(t): M-end, max slack
                __hip_atomic_store(&flags[bid], step + 1,
                                   __ATOMIC_RELAXED, __HIP_MEMORY_SCOPE_AGENT);
        }
    }
}

// ---------------------------------------------------------------- out proj + argmax -> mask
__global__ __launch_bounds__(256) void outproj_kernel(
    const float* __restrict__ x1, const float* __restrict__ out_w,
    const float* __restrict__ out_b, float* __restrict__ res,
    unsigned char* __restrict__ mask)
{
    const int tid  = threadIdx.x;
    const int lane = tid & 63;
    const int w    = tid >> 6;
    const int row  = blockIdx.x * 4 + w;     // b*S + s
    const float* xr = x1 + (size_t)row * 1024;
    float4 xv[4];
    #pragma unroll
    for (int i = 0; i < 4; ++i) xv[i] = *(const float4*)&xr[(i * 64 + lane) << 2];
    float best = -__builtin_inff();
    int bi = 0;
    #pragma unroll
    for (int l = 0; l < L_; ++l) {
        const float* wr = out_w + l * 1024;
        float s = 0.0f;
        #pragma unroll
        for (int i = 0; i < 4; ++i) {
            const float4 wv = *(const float4*)&wr[(i * 64 + lane) << 2];
            s = fmaf(xv[i].x, wv.x, s);
            s = fmaf(xv[i].y, wv.y, s);
            s = fmaf(xv[i].z, wv.z, s);
            s = fmaf(xv[i].w, wv.w, s);
        }
        #pragma unroll
        for (int d = 32; d >= 1; d >>= 1) s += __shfl_xor(s, d);
        s += out_b[l];
        if (lane == l) res[(size_t)row * L_ + l] = s;
        if (s > best) { best = s; bi = l; }     // strict > keeps first index (jnp.argmax)
    }
    if (lane == 0) mask[row] = (unsigned char)(bi != 0);
}

// ---------------------------------------------------------------- batched fp32 GEMM 128x128x8
// 256 threads, 8x8 microtile: 64 FMA per 4 ds_read_b128 per k.
// MODE 0: C = A @ B^T ; MODE 1: C = A @ B + D
template<int MODE>
__global__ __launch_bounds__(256) void gemm128(
    const float* __restrict__ A, const float* __restrict__ Bm,
    const float* __restrict__ D, float* __restrict__ C,
    const int M, const int N, const int K)
{
    const int bz = blockIdx.z;
    const float* Ab = A  + (size_t)bz * M * K;
    const float* Bb = Bm + (size_t)bz * N * K;
    const float* Db = (MODE == 1) ? (D + (size_t)bz * M * N) : (const float*)nullptr;
    float* Cb = C + (size_t)bz * M * N;
    const int m0 = blockIdx.y << 7;
    const int n0 = blockIdx.x << 7;
    const int tid = threadIdx.x;
    const int tm = tid >> 4, tn = tid & 15;      // 16x16 threads, 8x8 micro
    const int am = tid >> 1, ak = (tid & 1) << 2;   // A/B^T load: 128 rows x 8 cols
    const int bk1 = tid >> 5, bn1 = (tid & 31) << 2; // B (K,N) load: 8 rows x 128 cols
    __shared__ float As[8][132];
    __shared__ float Bs[8][132];
    float acc[8][8] = {};
    for (int k0 = 0; k0 < K; k0 += 8) {
        const float4 av = *(const float4*)&Ab[(size_t)(m0 + am) * K + k0 + ak];
        float4 bv;
        if (MODE == 0) bv = *(const float4*)&Bb[(size_t)(n0 + am) * K + k0 + ak];
        else           bv = *(const float4*)&Bb[(size_t)(k0 + bk1) * N + n0 + bn1];
        __syncthreads();
        As[ak + 0][am] = av.x; As[ak + 1][am] = av.y;
        As[ak + 2][am] = av.z; As[ak + 3][am] = av.w;
        if (MODE == 0) {
            Bs[ak + 0][am] = bv.x; Bs[ak + 1][am] = bv.y;
            Bs[ak + 2][am] = bv.z; Bs[ak + 3][am] = bv.w;
        } else {
            *(float4*)&Bs[bk1][bn1] = bv;
        }
        __syncthreads();
        #pragma unroll
        for (int k = 0; k < 8; ++k) {
            const float4 a0 = *(const float4*)&As[k][tm << 3];
            const float4 a1 = *(const float4*)&As[k][(tm << 3) + 4];
            const float4 b0 = *(const float4*)&Bs[k][tn << 3];
            const float4 b1 = *(const float4*)&Bs[k][(tn << 3) + 4];
            const float aa[8] = {a0.x, a0.y, a0.z, a0.w, a1.x, a1.y, a1.z, a1.w};
            const float bb[8] = {b0.x, b0.y, b0.z, b0.w, b1.x, b1.y, b1.z, b1.w};
            #pragma unroll
            for (int i = 0; i < 8; ++i)
                #pragma unroll
                for (int j = 0; j < 8; ++j)
                    acc[i][j] = fmaf(aa[i], bb[j], acc[i][j]);
        }
    }
    #pragma unroll
    for (int i = 0; i < 8; ++i) {
        const size_t ci = (size_t)(m0 + (tm << 3) + i) * N + n0 + (tn << 3);
        float4 o0 = make_float4(acc[i][0], acc[i][1], acc[i][2], acc[i][3]);
        float4 o1 = make_float4(acc[i][4], acc[i][5], acc[i][6], acc[i][7]);
        if (MODE == 1) {
            const float4 d0 = *(const float4*)&Db[ci];
            const float4 d1 = *(const float4*)&Db[ci + 4];
            o0.x += d0.x; o0.y += d0.y; o0.z += d0.z; o0.w += d0.w;
            o1.x += d1.x; o1.y += d1.y; o1.z += d1.z; o1.w += d1.w;
        }
        *(float4*)&Cb[ci] = o0;
        *(float4*)&Cb[ci + 4] = o1;
    }
}

// ---------------------------------------------------------------- dual masked softmax (in place)
__global__ __launch_bounds__(256) void softmax_kernel(float* __restrict__ sc,
                                                      const unsigned char* __restrict__ mask)
{
    const float INF = __builtin_inff();
    const int row = blockIdx.x;          // b*S + s
    const int b = row >> 10;
    float* pr = sc + (size_t)row * 1024;
    const unsigned char* mr = mask + b * 1024;
    const int tid = threadIdx.x;
    const int lane = tid & 63;
    const int w = tid >> 6;
    const int j0 = tid << 2;
    const float4 v = *(const float4*)&pr[j0];
    const unsigned mu = *(const unsigned*)&mr[j0];
    const bool m0 = (mu & 0xffu) != 0, m1 = ((mu >> 8) & 0xffu) != 0;
    const bool m2 = ((mu >> 16) & 0xffu) != 0, m3 = ((mu >> 24) & 0xffu) != 0;

    float mme = -INF, mot = -INF;
    if (m0) mme = fmaxf(mme, v.x); else mot = fmaxf(mot, v.x);
    if (m1) mme = fmaxf(mme, v.y); else mot = fmaxf(mot, v.y);
    if (m2) mme = fmaxf(mme, v.z); else mot = fmaxf(mot, v.z);
    if (m3) mme = fmaxf(mme, v.w); else mot = fmaxf(mot, v.w);
    #pragma unroll
    for (int d = 32; d >= 1; d >>= 1) {
        mme = fmaxf(mme, __shfl_xor(mme, d));
        mot = fmaxf(mot, __shfl_xor(mot, d));
    }
    __shared__ float sm[2][4];
    if (lane == 0) { sm[0][w] = mme; sm[1][w] = mot; }
    __syncthreads();
    float Mme = fmaxf(fmaxf(sm[0][0], sm[0][1]), fmaxf(sm[0][2], sm[0][3]));
    float Mot = fmaxf(fmaxf(sm[1][0], sm[1][1]), fmaxf(sm[1][2], sm[1][3]));
    const float MmeU = (Mme == -INF) ? 0.0f : Mme;
    const float MotU = (Mot == -INF) ? 0.0f : Mot;

    const float e0 = expf(v.x - (m0 ? MmeU : MotU));
    const float e1 = expf(v.y - (m1 ? MmeU : MotU));
    const float e2 = expf(v.z - (m2 ? MmeU : MotU));
    const float e3 = expf(v.w - (m3 ? MmeU : MotU));
    float sme = 0.0f, sot = 0.0f;
    if (m0) sme += e0; else sot += e0;
    if (m1) sme += e1; else sot += e1;
    if (m2) sme += e2; else sot += e2;
    if (m3) sme += e3; else sot += e3;
    #pragma unroll
    for (int d = 32; d >= 1; d >>= 1) {
        sme += __shfl_xor(sme, d);
        sot += __shfl_xor(sot, d);
    }
    __syncthreads();
    if (lane == 0) { sm[0][w] = sme; sm[1][w] = sot; }
    __syncthreads();
    const float Dme = sm[0][0] + sm[0][1] + sm[0][2] + sm[0][3];
    const float Dot = sm[1][0] + sm[1][1] + sm[1][2] + sm[1][3];

    float4 o;
    o.x = m0 ? (Dme > 0.0f ? e0 / Dme : 0.0f) : (Dot > 0.0f ? e0 / Dot : 0.0f);
    o.y = m1 ? (Dme > 0.0f ? e1 / Dme : 0.0f) : (Dot > 0.0f ? e1 / Dot : 0.0f);
    o.z = m2 ? (Dme > 0.0f ? e2 / Dme : 0.0f) : (Dot > 0.0f ? e2 / Dot : 0.0f);
    o.w = m3 ? (Dme > 0.0f ? e3 / Dme : 0.0f) : (Dot > 0.0f ? e3 / Dot : 0.0f);
    *(float4*)&pr[j0] = o;
}

// ---------------------------------------------------------------- launch
extern "C" void kernel_launch(void* const* d_in, const int* in_sizes, int n_in,
                              void* d_out, int out_size, void* d_ws, size_t ws_size,
                              hipStream_t stream)
{
    const float* emb     = (const float*)d_in[0];
    const float* wih_l0  = (const float*)d_in[1];
    const float* whh_l0  = (const float*)d_in[2];
    const float* bih_l0  = (const float*)d_in[3];
    const float* bhh_l0  = (const float*)d_in[4];
    const float* wih_l0r = (const float*)d_in[5];
    const float* whh_l0r = (const float*)d_in[6];
    const float* bih_l0r = (const float*)d_in[7];
    const float* bhh_l0r = (const float*)d_in[8];
    const float* wih_l1  = (const float*)d_in[9];
    const float* whh_l1  = (const float*)d_in[10];
    const float* bih_l1  = (const float*)d_in[11];
    const float* bhh_l1  = (const float*)d_in[12];
    const float* wih_l1r = (const float*)d_in[13];
    const float* whh_l1r = (const float*)d_in[14];
    const float* bih_l1r = (const float*)d_in[15];
    const float* bhh_l1r = (const float*)d_in[16];
    const float* out_w   = (const float*)d_in[17];
    const float* out_b   = (const float*)d_in[18];
    const int*   tokens  = (const int*)d_in[19];

    float* out     = (float*)d_out;
    float* A_out   = out;                          // (16,1024,1024)
    float* res_out = out + 16777216;               // (16,1024,10)

    float* ws = (float*)d_ws;
    float* x0 = ws;                                //  8,388,608 f
    float* h0 = ws + 8388608;                      // 16,777,216 f
    float* x1 = h0 + 16777216;                     // 16,777,216 f
    float* sc = x1 + 16777216;                     // 16,777,216 f (scores, then P in place)
    unsigned char* mask = (unsigned char*)(sc + 16777216);   // 16,384 B
    int* flags0 = (int*)(mask + 16384);            // 256 ints
    int* flags1 = flags0 + 256;

    (void)in_sizes; (void)n_in; (void)out_size; (void)ws_size;

    (void)hipMemsetAsync(flags0, 0, 512 * sizeof(int), stream);

    embed_kernel<<<B_ * S_, 128, 0, stream>>>(tokens, emb, x0);

    lstm_bidir<512><<<256, 512, 0, stream>>>(
        x0, wih_l0, whh_l0, bih_l0, bhh_l0,
        wih_l0r, whh_l0r, bih_l0r, bhh_l0r, h0, flags0);

    lstm_bidir<1024><<<256, 512, 0, stream>>>(
        h0, wih_l1, whh_l1, bih_l1, bhh_l1,
        wih_l1r, whh_l1r, bih_l1r, bhh_l1r, x1, flags1);

    outproj_kernel<<<(B_ * S_) / 4, 256, 0, stream>>>(x1, out_w, out_b, res_out, mask);

    dim3 gg(8, 8, 16);
    gemm128<0><<<gg, 256, 0, stream>>>(x1, x1, nullptr, sc, 1024, 1024, 1024);

    softmax_kernel<<<B_ * S_, 256, 0, stream>>>(sc, mask);

    gemm128<1><<<gg, 256, 0, stream>>>(sc, x1, x1, A_out, 1024, 1024, 1024);
}